// Round 10
// baseline (467.499 us; speedup 1.0000x reference)
//
#include <hip/hip_runtime.h>

#define N_NODES 50000
#define N_EDGES 800000
#define IN_C 256
#define HID_C 512
#define OUT_C 256
#define M_PAD 50048   // 391 * 128, covers 50000 with one padded tile
#define NPASS 8
#define PASS_SHIFT 13   // src >> 13 -> bucket (8192-node source windows)

typedef unsigned short u16;
typedef unsigned int   u32;
typedef u16  u16x4 __attribute__((ext_vector_type(4)));
typedef u16  u16x8 __attribute__((ext_vector_type(8)));
typedef short s16x8 __attribute__((ext_vector_type(8)));   // bf16 MFMA frag (guide §3)
typedef float f32x4 __attribute__((ext_vector_type(4)));

__device__ __forceinline__ float bf2f(u16 h) {
    u32 u = ((u32)h) << 16;
    return __builtin_bit_cast(float, u);
}
__device__ __forceinline__ u16 f2bf(float f) {   // round-to-nearest-even
    u32 u = __builtin_bit_cast(u32, f);
    u32 r = u + 0x7fffu + ((u >> 16) & 1u);
    return (u16)(r >> 16);
}
__device__ __forceinline__ void gload16(const void* g, void* l) {
    __builtin_amdgcn_global_load_lds(
        (const __attribute__((address_space(1))) u32*)g,
        (__attribute__((address_space(3))) u32*)l, 16, 0, 0);
}

// ---------------- sub-CSR build: buckets (dst, src>>13) ----------------
// col ends up sorted by (dst, src>>13): per node the edge list is contiguous
// [rp8[n*8], rp8[n*8+8]) AND pass-sorted (source-window-ascending).
__global__ void k_hist8(const int* __restrict__ src, const int* __restrict__ dst,
                        int* __restrict__ cnt8) {
    int e = blockIdx.x * 256 + threadIdx.x;
    if (e < N_EDGES) {
        int q = src[e] >> PASS_SHIFT;
        atomicAdd(&cnt8[dst[e] * NPASS + q], 1);
    }
}

__global__ void k_partial(const int* __restrict__ cnt, int* __restrict__ bsum, int total) {
    __shared__ int s[256];
    int i = blockIdx.x * 256 + threadIdx.x;
    int v = (i < total) ? cnt[i] : 0;
    s[threadIdx.x] = v; __syncthreads();
    for (int o = 128; o > 0; o >>= 1) {
        if (threadIdx.x < o) s[threadIdx.x] += s[threadIdx.x + o];
        __syncthreads();
    }
    if (threadIdx.x == 0) bsum[blockIdx.x] = s[0];
}

// exclusive scan of nb block sums (nb may exceed 256): chunked Hillis-Steele + carry
__global__ void k_scanb(int* __restrict__ bsum, int nb) {
    __shared__ int s[256];
    int carry = 0;
    for (int base = 0; base < nb; base += 256) {
        int i = base + threadIdx.x;
        int v = (i < nb) ? bsum[i] : 0;
        s[threadIdx.x] = v; __syncthreads();
        for (int o = 1; o < 256; o <<= 1) {
            int t = (threadIdx.x >= o) ? s[threadIdx.x - o] : 0;
            __syncthreads();
            s[threadIdx.x] += t;
            __syncthreads();
        }
        int tot = s[255];
        if (i < nb) bsum[i] = s[threadIdx.x] - v + carry;
        carry += tot;
        __syncthreads();
    }
}

__global__ void k_rowptr8(const int* __restrict__ cnt, const int* __restrict__ bsum,
                          int* __restrict__ rp, int* __restrict__ cur, int total) {
    __shared__ int s[256];
    int i = blockIdx.x * 256 + threadIdx.x;
    int v = (i < total) ? cnt[i] : 0;
    s[threadIdx.x] = v; __syncthreads();
    for (int o = 1; o < 256; o <<= 1) {                     // Hillis-Steele inclusive
        int t = (threadIdx.x >= o) ? s[threadIdx.x - o] : 0;
        __syncthreads();
        s[threadIdx.x] += t;
        __syncthreads();
    }
    int excl = s[threadIdx.x] - v + bsum[blockIdx.x];
    if (i < total) { rp[i] = excl; cur[i] = excl; }
    if (i == total - 1) rp[total] = excl + v;
}

__global__ void k_scatter8(const int* __restrict__ src, const int* __restrict__ dst,
                           int* __restrict__ cur, int* __restrict__ col) {
    int e = blockIdx.x * 256 + threadIdx.x;
    if (e < N_EDGES) {
        int sv = src[e];
        int q = sv >> PASS_SHIFT;
        int p = atomicAdd(&cur[dst[e] * NPASS + q], 1);
        col[p] = sv;
    }
}

// ------- degree-sorted node permutation (kills intra-wave divergence) -------
// LDS pre-aggregation: one global atomic per non-empty bin per block.
__global__ void k_deg(const int* __restrict__ rp8, int* __restrict__ dbin) {
    __shared__ int lbin[256];
    int t = threadIdx.x;
    lbin[t] = 0; __syncthreads();
    int n = blockIdx.x * 256 + t;
    if (n < N_NODES) {
        int deg = rp8[n * NPASS + NPASS] - rp8[n * NPASS];
        if (deg > 255) deg = 255;
        atomicAdd(&lbin[deg], 1);          // LDS atomic (on-CU)
    }
    __syncthreads();
    int c = lbin[t];
    if (c > 0) atomicAdd(&dbin[t], c);     // <=256 global atomics / block
}

__global__ void k_degscan(const int* __restrict__ dbin, int* __restrict__ dcur) {
    __shared__ int s[256];
    int i = threadIdx.x;
    int v = dbin[i];
    s[i] = v; __syncthreads();
    for (int o = 1; o < 256; o <<= 1) {
        int t = (i >= o) ? s[i - o] : 0;
        __syncthreads();
        s[i] += t;
        __syncthreads();
    }
    dcur[i] = s[i] - v;   // exclusive
}

__global__ void k_degscatter(const int* __restrict__ rp8, int* __restrict__ dcur,
                             int* __restrict__ perm) {
    __shared__ int lbin[256];
    __shared__ int lbase[256];
    int t = threadIdx.x;
    lbin[t] = 0; __syncthreads();
    int n = blockIdx.x * 256 + t;
    int deg = 0, lrank = 0;
    bool valid = (n < N_NODES);
    if (valid) {
        deg = rp8[n * NPASS + NPASS] - rp8[n * NPASS];
        if (deg > 255) deg = 255;
        lrank = atomicAdd(&lbin[deg], 1);  // LDS atomic -> local rank
    }
    __syncthreads();
    int c = lbin[t];
    lbase[t] = (c > 0) ? atomicAdd(&dcur[t], c) : 0;  // reserve range per bin
    __syncthreads();
    if (valid) perm[lbase[deg] + lrank] = n;
}

// ------ merged prep: w1t/w2t/w3t transposed bf16 + x -> bf16 (one launch) ------
__device__ __forceinline__ void wt_body(const float* w, u16* wt, int K, int N, int idx) {
    if (idx >= K * N) return;
    int n = idx / K, k = idx - n * K;
    wt[idx] = f2bf(w[(size_t)k * N + n]);
}

__global__ void k_prep(const float* __restrict__ w1, const float* __restrict__ w2,
                       const float* __restrict__ w3, const float* __restrict__ x,
                       u16* __restrict__ w1t, u16* __restrict__ w2t,
                       u16* __restrict__ w3t, u16* __restrict__ xb) {
    int b = blockIdx.x, t = threadIdx.x;
    if (b < 512) {
        wt_body(w1, w1t, IN_C, HID_C, b * 256 + t);
    } else if (b < 1536) {
        wt_body(w2, w2t, HID_C, HID_C, (b - 512) * 256 + t);
    } else if (b < 2048) {
        wt_body(w3, w3t, HID_C, OUT_C, (b - 1536) * 256 + t);
    } else {
        int i = (b - 2048) * 256 + t;
        if (i < N_NODES * IN_C / 4) {
            float4 v = ((const float4*)x)[i];
            u16x4 o;
            o[0] = f2bf(v.x); o[1] = f2bf(v.y); o[2] = f2bf(v.z); o[3] = f2bf(v.w);
            ((u16x4*)xb)[i] = o;
        }
    }
}

// ---- streaming slab gather (XCD-private lines + degree-sorted nodes) ----
// 128-B slabs: C=512 -> 8 slabs, slab=bid&7 -> each line pulled by exactly one
// XCD; C=256 -> 4 slabs, 2 XCDs per slab.
// One node per 8-LANE group (32 nodes/block, 8 nodes/wave); lane owns 8 ch
// (16 B = dwordx4). vs r9's 16-lane/8B: per-edge VMEM instruction count
// halves, in-flight lines per wave doubles (32 at 4-deep unroll). Degree-
// sorted perm keeps the 8 groups/wave convergent (r7's failure mode fixed).
// No nontemporal, no alignment prologue (r7's other failure modes).
// EPI 0: out bf16 = bf16(ep*self + agg).  EPI 1: out fp32 = ep*self + agg + bias.
template <int C, int EPI>
__global__ __launch_bounds__(256) void k_agg_stream(
    const u16* __restrict__ sm, const int* __restrict__ rp8,
    const int* __restrict__ col, const int* __restrict__ perm,
    const float* __restrict__ eps, const float* __restrict__ bias,
    void* __restrict__ out) {
    constexpr int NSLAB = C / 64;          // 128-B slabs
    const int slab  = blockIdx.x & (NSLAB - 1);
    const int chunk = blockIdx.x / NSLAB;
    const int gid = threadIdx.x >> 3;      // 32 groups of 8 lanes
    const int ln  = threadIdx.x & 7;
    const int ch0 = slab * 64 + ln * 8;
    const int ni = chunk * 32 + gid;
    if (ni >= N_NODES) return;
    const int n = perm[ni];
    const float ep = 1.f + eps[0];

    const int rs = rp8[n * NPASS];
    const int re = rp8[n * NPASS + NPASS];
    float a[8];
#pragma unroll
    for (int j = 0; j < 8; j++) a[j] = 0.f;

    int e = rs;
    for (; e + 4 <= re; e += 4) {
        int s0 = col[e], s1 = col[e + 1], s2 = col[e + 2], s3 = col[e + 3];
        u16x8 v0 = *(const u16x8*)(sm + (size_t)s0 * C + ch0);
        u16x8 v1 = *(const u16x8*)(sm + (size_t)s1 * C + ch0);
        u16x8 v2 = *(const u16x8*)(sm + (size_t)s2 * C + ch0);
        u16x8 v3 = *(const u16x8*)(sm + (size_t)s3 * C + ch0);
#pragma unroll
        for (int j = 0; j < 8; j++)
            a[j] += (bf2f(v0[j]) + bf2f(v1[j])) + (bf2f(v2[j]) + bf2f(v3[j]));
    }
    for (; e < re; e++) {
        int s0 = col[e];
        u16x8 v0 = *(const u16x8*)(sm + (size_t)s0 * C + ch0);
#pragma unroll
        for (int j = 0; j < 8; j++) a[j] += bf2f(v0[j]);
    }

    u16x8 sv = *(const u16x8*)(sm + (size_t)n * C + ch0);
    float r[8];
#pragma unroll
    for (int j = 0; j < 8; j++) r[j] = fmaf(ep, bf2f(sv[j]), a[j]);

    if constexpr (EPI == 0) {
        u16x8 o;
#pragma unroll
        for (int j = 0; j < 8; j++) o[j] = f2bf(r[j]);
        *(u16x8*)((u16*)out + (size_t)n * C + ch0) = o;
    } else {
        float4 b0 = *(const float4*)(bias + ch0);
        float4 b1 = *(const float4*)(bias + ch0 + 4);
        float* orow = (float*)out + (size_t)n * C + ch0;
        float4 o0, o1;
        o0.x = r[0] + b0.x; o0.y = r[1] + b0.y; o0.z = r[2] + b0.z; o0.w = r[3] + b0.w;
        o1.x = r[4] + b1.x; o1.y = r[5] + b1.y; o1.z = r[6] + b1.z; o1.w = r[7] + b1.w;
        *(float4*)orow = o0;
        *(float4*)(orow + 4) = o1;
    }
}

// -------------- bf16 MFMA GEMM: C[M][N] = A[M][K] @ Wt[N][K]^T --------------
// 128x128 tile, BK=64 (32 MFMA per vmcnt/barrier drain), 4 waves (2x2).
// Staging: global_load_lds w16, linear LDS dest, chunk-XOR swizzle c^=(r&7)
// applied on BOTH global source and ds_read (rule 21) -> 2-way (free) banks.
// Epilogue: acc -> bf16 -> LDS C-tile [128][130] (pad => conflict-free b128
// readback), then coalesced u16x8 global stores.
// EPI=0: out bf16 = relu(acc + bias).  EPI=1: out bf16 = acc.
template <int K, int EPI>
__global__ __launch_bounds__(256, 2) void gemm_k(
    const u16* __restrict__ A, const u16* __restrict__ Wt,
    const float* __restrict__ bias, void* __restrict__ out,
    int N, int grid_n) {
    __shared__ u16 smem[16640];            // max(Als+Bls = 16384, Cls = 16640)
    u16* Als = smem;                       // [128][64]
    u16* Bls = smem + 8192;                // [128][64]
    const int tid  = threadIdx.x;
    const int wave = tid >> 6, lane = tid & 63;
    const int wm = wave >> 1, wn = wave & 1;
    const int bm = blockIdx.x / grid_n, bn = blockIdx.x % grid_n;
    const int m0 = bm * 128, n0 = bn * 128;
    const int sr = lane >> 3, sc = lane & 7;       // staging: 8 rows x 8 chunks
    const int fr = lane & 15, kg = lane >> 4;      // fragment coords

    f32x4 acc[4][4];
#pragma unroll
    for (int i = 0; i < 4; i++)
#pragma unroll
        for (int j = 0; j < 4; j++) acc[i][j] = (f32x4){0.f, 0.f, 0.f, 0.f};

    for (int kk = 0; kk < K; kk += 64) {
#pragma unroll
        for (int i = 0; i < 4; i++) {
            int rl = wave * 32 + i * 8 + sr;
            int cs = sc ^ (rl & 7);                 // pre-swizzled global source
            gload16(A  + (size_t)(m0 + rl) * K + kk + cs * 8,
                    &Als[(wave * 32 + i * 8) * 64]);
            gload16(Wt + (size_t)(n0 + rl) * K + kk + cs * 8,
                    &Bls[(wave * 32 + i * 8) * 64]);
        }
        asm volatile("s_waitcnt vmcnt(0)" ::: "memory");
        __syncthreads();

#pragma unroll
        for (int k2 = 0; k2 < 2; k2++) {
            s16x8 af[4], bfr[4];
#pragma unroll
            for (int mi = 0; mi < 4; mi++) {
                int r = wm * 64 + mi * 16 + fr;
                int c = (k2 * 4 + kg) ^ (r & 7);    // swizzled read
                af[mi] = *(const s16x8*)&Als[r * 64 + c * 8];
            }
#pragma unroll
            for (int ni = 0; ni < 4; ni++) {
                int r = wn * 64 + ni * 16 + fr;
                int c = (k2 * 4 + kg) ^ (r & 7);
                bfr[ni] = *(const s16x8*)&Bls[r * 64 + c * 8];
            }
#pragma unroll
            for (int mi = 0; mi < 4; mi++)
#pragma unroll
                for (int ni = 0; ni < 4; ni++)
                    acc[mi][ni] = __builtin_amdgcn_mfma_f32_16x16x32_bf16(
                        af[mi], bfr[ni], acc[mi][ni], 0, 0, 0);
        }
        __syncthreads();
    }

    // epilogue: C row = kg*4 + j, col = fr (m89/m91-verified C/D layout)
    // bounce through LDS [128][130] for coalesced output
    u16* Cls = smem;
#pragma unroll
    for (int ni = 0; ni < 4; ni++) {
        int c = wn * 64 + ni * 16 + fr;
        float bv = 0.f;
        if constexpr (EPI == 0) bv = bias[n0 + c];
#pragma unroll
        for (int mi = 0; mi < 4; mi++) {
#pragma unroll
            for (int j = 0; j < 4; j++) {
                int r = wm * 64 + mi * 16 + kg * 4 + j;
                float v = acc[mi][ni][j];
                if constexpr (EPI == 0) {
                    v += bv;
                    v = v > 0.f ? v : 0.f;
                }
                Cls[r * 130 + c] = f2bf(v);
            }
        }
    }
    __syncthreads();

    const int r2 = tid >> 1;                  // 0..127
    const int cb = (tid & 1) * 64;            // two 64-col halves
    if (m0 + r2 < N_NODES) {
        u16* orow = (u16*)out + (size_t)(m0 + r2) * N + n0 + cb;
#pragma unroll
        for (int k = 0; k < 8; k++) {
            u16x8 val = *(const u16x8*)&Cls[r2 * 130 + cb + k * 8];
            *(u16x8*)(orow + k * 8) = val;
        }
    }
}

// ---------------- launch ----------------
extern "C" void kernel_launch(void* const* d_in, const int* in_sizes, int n_in,
                              void* d_out, int out_size, void* d_ws, size_t ws_size,
                              hipStream_t stream) {
    const float* x    = (const float*)d_in[0];
    const int*   src  = (const int*)d_in[1];
    const int*   dst  = (const int*)d_in[2];
    const float* w1   = (const float*)d_in[3];
    const float* b1   = (const float*)d_in[4];
    const float* eps1 = (const float*)d_in[5];
    const float* w2   = (const float*)d_in[6];
    const float* b2   = (const float*)d_in[7];
    const float* eps2 = (const float*)d_in[8];
    const float* w3   = (const float*)d_in[9];
    const float* b3   = (const float*)d_in[10];
    const float* eps3 = (const float*)d_in[11];

    char* ws = (char*)d_ws;
    size_t off = 0;
    auto take = [&](size_t bytes) {
        char* p = ws + off;
        off += (bytes + 255) & ~(size_t)255;
        return p;
    };
    const int TOT8 = N_NODES * NPASS;                 // 400000 buckets
    int* cnt8 = (int*)take((size_t)TOT8 * 4);
    int* rp8  = (int*)take((size_t)(TOT8 + 1) * 4);
    int* cur8 = (int*)take((size_t)TOT8 * 4);
    int* bsum = (int*)take(2048 * 4);
    int* col  = (int*)take((size_t)N_EDGES * 4);
    int* dbin = (int*)take(256 * 4);
    int* dcur = (int*)take(256 * 4);
    int* perm = (int*)take((size_t)N_NODES * 4);
    u16* w1t  = (u16*)take((size_t)IN_C * HID_C * 2);
    u16* w2t  = (u16*)take((size_t)HID_C * HID_C * 2);
    u16* w3t  = (u16*)take((size_t)HID_C * OUT_C * 2);
    u16* A0   = (u16*)take((size_t)M_PAD * IN_C * 2);
    u16* h1   = (u16*)take((size_t)M_PAD * HID_C * 2);
    u16* A1   = (u16*)take((size_t)M_PAD * HID_C * 2);
    // time-shared buffer: xb (phase 1) -> A1 (phase 2) -> g3 bf16 (phase 3).
    // each is fully dead before the next is written; stream order serializes.
    u16* xb = A1;            // 25.6 MB <= 51.2 MB, dead after l1 agg
    u16* h2 = h1;            // GEMM2 reads only A1 -> safe alias
    u16* g3 = A1;            // GEMM3 reads only h2 -> safe alias

    const int NB8 = (TOT8 + 255) / 256;   // 1563 scan blocks
    const int NE  = (N_EDGES + 255) / 256;
    const int NBN = (N_NODES + 255) / 256;

    hipMemsetAsync(cnt8, 0, (size_t)TOT8 * 4, stream);
    hipMemsetAsync(dbin, 0, 256 * 4, stream);
    k_hist8  <<<NE, 256, 0, stream>>>(src, dst, cnt8);
    k_partial<<<NB8, 256, 0, stream>>>(cnt8, bsum, TOT8);
    k_scanb  <<<1, 256, 0, stream>>>(bsum, NB8);
    k_rowptr8<<<NB8, 256, 0, stream>>>(cnt8, bsum, rp8, cur8, TOT8);
    k_scatter8<<<NE, 256, 0, stream>>>(src, dst, cur8, col);

    // degree-sorted node permutation (uses rp8 only; LDS-pre-aggregated atomics)
    k_deg       <<<NBN, 256, 0, stream>>>(rp8, dbin);
    k_degscan   <<<1, 256, 0, stream>>>(dbin, dcur);
    k_degscatter<<<NBN, 256, 0, stream>>>(rp8, dcur, perm);

    // merged prep: 2048 weight-transpose blocks + 12500 x->bf16 blocks
    k_prep<<<2048 + 12500, 256, 0, stream>>>(w1, w2, w3, x, w1t, w2t, w3t, xb);

    // agg grids: 32 nodes/block; C=512 -> 1563 chunks x 8 slabs; C=256 -> x 4
    const int NCH  = (N_NODES + 31) / 32;   // 1563
    const int G512 = NCH * 8;
    const int G256 = NCH * 4;

    // layer 1: aggregate (256ch bf16) then GEMM -> h1 = relu(A0 @ W1 + b1)
    k_agg_stream<IN_C, 0><<<G256, 256, 0, stream>>>(
        xb, rp8, col, perm, eps1, nullptr, A0);
    gemm_k<IN_C, 0><<<391 * (HID_C / 128), 256, 0, stream>>>(
        A0, w1t, b1, h1, HID_C, HID_C / 128);

    // layer 2: aggregate (512ch) then GEMM -> h2 = relu(A1 @ W2 + b2)
    k_agg_stream<HID_C, 0><<<G512, 256, 0, stream>>>(
        h1, rp8, col, perm, eps2, nullptr, A1);
    gemm_k<HID_C, 0><<<391 * (HID_C / 128), 256, 0, stream>>>(
        A1, w2t, b2, h2, HID_C, HID_C / 128);

    // layer 3: GEMM first (g3 = h2 @ W3 bf16, no bias), then aggregate + bias -> fp32
    gemm_k<HID_C, 1><<<391 * (OUT_C / 128), 256, 0, stream>>>(
        h2, w3t, nullptr, g3, OUT_C, OUT_C / 128);
    k_agg_stream<OUT_C, 1><<<G256, 256, 0, stream>>>(
        g3, rp8, col, perm, eps3, b3, (float*)d_out);
}

// Round 11
// 440.162 us; speedup vs baseline: 1.0621x; 1.0621x over previous
//
#include <hip/hip_runtime.h>

#define N_NODES 50000
#define N_EDGES 800000
#define IN_C 256
#define HID_C 512
#define OUT_C 256
#define M_PAD 50048   // 391 * 128, covers 50000 with one padded tile
#define NPASS 8
#define PASS_SHIFT 13   // src >> 13 -> bucket (8192-node source windows)
#define SEG 1024        // local degree-sort segment

typedef unsigned short u16;
typedef unsigned int   u32;
typedef u16  u16x4 __attribute__((ext_vector_type(4)));
typedef u16  u16x8 __attribute__((ext_vector_type(8)));
typedef short s16x8 __attribute__((ext_vector_type(8)));   // bf16 MFMA frag (guide §3)
typedef float f32x4 __attribute__((ext_vector_type(4)));

__device__ __forceinline__ float bf2f(u16 h) {
    u32 u = ((u32)h) << 16;
    return __builtin_bit_cast(float, u);
}
__device__ __forceinline__ u16 f2bf(float f) {   // round-to-nearest-even
    u32 u = __builtin_bit_cast(u32, f);
    u32 r = u + 0x7fffu + ((u >> 16) & 1u);
    return (u16)(r >> 16);
}
__device__ __forceinline__ void gload16(const void* g, void* l) {
    __builtin_amdgcn_global_load_lds(
        (const __attribute__((address_space(1))) u32*)g,
        (__attribute__((address_space(3))) u32*)l, 16, 0, 0);
}

// ---------------- sub-CSR build: buckets (dst, src>>13) ----------------
// col ends up sorted by (dst, src>>13): per node the edge list is contiguous
// [rp8[n*8], rp8[n*8+8]) AND pass-sorted (source-window-ascending).
__global__ void k_hist8(const int* __restrict__ src, const int* __restrict__ dst,
                        int* __restrict__ cnt8) {
    int e = blockIdx.x * 256 + threadIdx.x;
    if (e < N_EDGES) {
        int q = src[e] >> PASS_SHIFT;
        atomicAdd(&cnt8[dst[e] * NPASS + q], 1);
    }
}

__global__ void k_partial(const int* __restrict__ cnt, int* __restrict__ bsum, int total) {
    __shared__ int s[256];
    int i = blockIdx.x * 256 + threadIdx.x;
    int v = (i < total) ? cnt[i] : 0;
    s[threadIdx.x] = v; __syncthreads();
    for (int o = 128; o > 0; o >>= 1) {
        if (threadIdx.x < o) s[threadIdx.x] += s[threadIdx.x + o];
        __syncthreads();
    }
    if (threadIdx.x == 0) bsum[blockIdx.x] = s[0];
}

// exclusive scan of nb block sums (nb may exceed 256): chunked Hillis-Steele + carry
__global__ void k_scanb(int* __restrict__ bsum, int nb) {
    __shared__ int s[256];
    int carry = 0;
    for (int base = 0; base < nb; base += 256) {
        int i = base + threadIdx.x;
        int v = (i < nb) ? bsum[i] : 0;
        s[threadIdx.x] = v; __syncthreads();
        for (int o = 1; o < 256; o <<= 1) {
            int t = (threadIdx.x >= o) ? s[threadIdx.x - o] : 0;
            __syncthreads();
            s[threadIdx.x] += t;
            __syncthreads();
        }
        int tot = s[255];
        if (i < nb) bsum[i] = s[threadIdx.x] - v + carry;
        carry += tot;
        __syncthreads();
    }
}

__global__ void k_rowptr8(const int* __restrict__ cnt, const int* __restrict__ bsum,
                          int* __restrict__ rp, int* __restrict__ cur, int total) {
    __shared__ int s[256];
    int i = blockIdx.x * 256 + threadIdx.x;
    int v = (i < total) ? cnt[i] : 0;
    s[threadIdx.x] = v; __syncthreads();
    for (int o = 1; o < 256; o <<= 1) {                     // Hillis-Steele inclusive
        int t = (threadIdx.x >= o) ? s[threadIdx.x - o] : 0;
        __syncthreads();
        s[threadIdx.x] += t;
        __syncthreads();
    }
    int excl = s[threadIdx.x] - v + bsum[blockIdx.x];
    if (i < total) { rp[i] = excl; cur[i] = excl; }
    if (i == total - 1) rp[total] = excl + v;
}

__global__ void k_scatter8(const int* __restrict__ src, const int* __restrict__ dst,
                           int* __restrict__ cur, int* __restrict__ col) {
    int e = blockIdx.x * 256 + threadIdx.x;
    if (e < N_EDGES) {
        int sv = src[e];
        int q = sv >> PASS_SHIFT;
        int p = atomicAdd(&cur[dst[e] * NPASS + q], 1);
        col[p] = sv;
    }
}

// ---- segment-local degree sort: convergence (r9) + locality (r5) ----
// Sort nodes by degree WITHIN 1024-node segments only. Wave groups get
// near-equal degrees (local dist ~ global) while all node-indexed traffic
// (self-reads, writes) stays in a 128KB/slab window -> L2-hot. One kernel,
// pure LDS (no global atomics). Rank ties nondeterministic but perm is a
// scheduling permutation only -> per-node output unchanged (bit-exact).
__global__ __launch_bounds__(256) void k_locsort(const int* __restrict__ rp8,
                                                 int* __restrict__ perm) {
    __shared__ int bins[256];
    __shared__ int s[256];
    const int t = threadIdx.x;
    const int n0 = blockIdx.x * SEG;
    bins[t] = 0; __syncthreads();
    int deg[4];
#pragma unroll
    for (int i = 0; i < 4; i++) {
        int n = n0 + i * 256 + t;
        deg[i] = 0;
        if (n < N_NODES) {
            int d = rp8[n * NPASS + NPASS] - rp8[n * NPASS];
            if (d > 255) d = 255;
            deg[i] = d;
            atomicAdd(&bins[d], 1);        // LDS atomic
        }
    }
    __syncthreads();
    int v = bins[t];
    s[t] = v; __syncthreads();
    for (int o = 1; o < 256; o <<= 1) {    // Hillis-Steele inclusive scan
        int u = (t >= o) ? s[t - o] : 0;
        __syncthreads();
        s[t] += u;
        __syncthreads();
    }
    bins[t] = s[t] - v;                    // exclusive base -> running counter
    __syncthreads();
#pragma unroll
    for (int i = 0; i < 4; i++) {
        int n = n0 + i * 256 + t;
        if (n < N_NODES) {
            int pos = atomicAdd(&bins[deg[i]], 1);
            perm[n0 + pos] = n;
        }
    }
}

// ------ merged prep: w1t/w2t/w3t transposed bf16 + x -> bf16 (one launch) ------
__device__ __forceinline__ void wt_body(const float* w, u16* wt, int K, int N, int idx) {
    if (idx >= K * N) return;
    int n = idx / K, k = idx - n * K;
    wt[idx] = f2bf(w[(size_t)k * N + n]);
}

__global__ void k_prep(const float* __restrict__ w1, const float* __restrict__ w2,
                       const float* __restrict__ w3, const float* __restrict__ x,
                       u16* __restrict__ w1t, u16* __restrict__ w2t,
                       u16* __restrict__ w3t, u16* __restrict__ xb) {
    int b = blockIdx.x, t = threadIdx.x;
    if (b < 512) {
        wt_body(w1, w1t, IN_C, HID_C, b * 256 + t);
    } else if (b < 1536) {
        wt_body(w2, w2t, HID_C, HID_C, (b - 512) * 256 + t);
    } else if (b < 2048) {
        wt_body(w3, w3t, HID_C, OUT_C, (b - 1536) * 256 + t);
    } else {
        int i = (b - 2048) * 256 + t;
        if (i < N_NODES * IN_C / 4) {
            float4 v = ((const float4*)x)[i];
            u16x4 o;
            o[0] = f2bf(v.x); o[1] = f2bf(v.y); o[2] = f2bf(v.z); o[3] = f2bf(v.w);
            ((u16x4*)xb)[i] = o;
        }
    }
}

// ---- streaming slab gather (XCD-private lines + segment-local degree sort) ----
// 128-B slabs: C=512 -> 8 slabs, slab=bid&7 -> each line pulled by exactly one
// XCD; C=256 -> 4 slabs, 2 XCDs per slab.
// One node per 16-lane group (16 nodes/block); lane owns 4 ch (8 B) — r9 form
// (measured faster than 8-lane/16B, r10). Edges contiguous & pass-sorted.
// EPI 0: out bf16 = bf16(ep*self + agg).  EPI 1: out fp32 = ep*self + agg + bias.
template <int C, int EPI>
__global__ __launch_bounds__(256) void k_agg_stream(
    const u16* __restrict__ sm, const int* __restrict__ rp8,
    const int* __restrict__ col, const int* __restrict__ perm,
    const float* __restrict__ eps, const float* __restrict__ bias,
    void* __restrict__ out) {
    constexpr int NSLAB = C / 64;          // 128-B slabs
    const int slab  = blockIdx.x & (NSLAB - 1);
    const int chunk = blockIdx.x / NSLAB;
    const int gid = threadIdx.x >> 4;      // 16 groups of 16 lanes
    const int ln  = threadIdx.x & 15;
    const int ch0 = slab * 64 + ln * 4;
    const int ni = chunk * 16 + gid;
    if (ni >= N_NODES) return;
    const int n = perm[ni];
    const float ep = 1.f + eps[0];

    const int rs = rp8[n * NPASS];
    const int re = rp8[n * NPASS + NPASS];
    float a0 = 0.f, a1 = 0.f, a2 = 0.f, a3 = 0.f;
    int e = rs;
    for (; e + 4 <= re; e += 4) {
        int s0 = col[e], s1 = col[e + 1], s2 = col[e + 2], s3 = col[e + 3];
        u16x4 v0 = *(const u16x4*)(sm + (size_t)s0 * C + ch0);
        u16x4 v1 = *(const u16x4*)(sm + (size_t)s1 * C + ch0);
        u16x4 v2 = *(const u16x4*)(sm + (size_t)s2 * C + ch0);
        u16x4 v3 = *(const u16x4*)(sm + (size_t)s3 * C + ch0);
        a0 += bf2f(v0[0]) + bf2f(v1[0]) + bf2f(v2[0]) + bf2f(v3[0]);
        a1 += bf2f(v0[1]) + bf2f(v1[1]) + bf2f(v2[1]) + bf2f(v3[1]);
        a2 += bf2f(v0[2]) + bf2f(v1[2]) + bf2f(v2[2]) + bf2f(v3[2]);
        a3 += bf2f(v0[3]) + bf2f(v1[3]) + bf2f(v2[3]) + bf2f(v3[3]);
    }
    for (; e < re; e++) {
        int s0 = col[e];
        u16x4 v0 = *(const u16x4*)(sm + (size_t)s0 * C + ch0);
        a0 += bf2f(v0[0]); a1 += bf2f(v0[1]); a2 += bf2f(v0[2]); a3 += bf2f(v0[3]);
    }

    u16x4 sv = *(const u16x4*)(sm + (size_t)n * C + ch0);
    float r0 = fmaf(ep, bf2f(sv[0]), a0);
    float r1 = fmaf(ep, bf2f(sv[1]), a1);
    float r2 = fmaf(ep, bf2f(sv[2]), a2);
    float r3 = fmaf(ep, bf2f(sv[3]), a3);
    if constexpr (EPI == 0) {
        u16x4 o;
        o[0] = f2bf(r0); o[1] = f2bf(r1); o[2] = f2bf(r2); o[3] = f2bf(r3);
        *(u16x4*)((u16*)out + (size_t)n * C + ch0) = o;
    } else {
        float4 bv = *(const float4*)(bias + ch0);
        float4 o;
        o.x = r0 + bv.x; o.y = r1 + bv.y; o.z = r2 + bv.z; o.w = r3 + bv.w;
        *(float4*)((float*)out + (size_t)n * C + ch0) = o;
    }
}

// -------------- bf16 MFMA GEMM: C[M][N] = A[M][K] @ Wt[N][K]^T --------------
// 128x128 tile, BK=64 (32 MFMA per vmcnt/barrier drain), 4 waves (2x2).
// Staging: global_load_lds w16, linear LDS dest, chunk-XOR swizzle c^=(r&7)
// applied on BOTH global source and ds_read (rule 21) -> 2-way (free) banks.
// Epilogue: acc -> bf16 -> LDS C-tile [128][130] (pad => conflict-free b128
// readback), then coalesced u16x8 global stores.
// EPI=0: out bf16 = relu(acc + bias).  EPI=1: out bf16 = acc.
template <int K, int EPI>
__global__ __launch_bounds__(256, 2) void gemm_k(
    const u16* __restrict__ A, const u16* __restrict__ Wt,
    const float* __restrict__ bias, void* __restrict__ out,
    int N, int grid_n) {
    __shared__ u16 smem[16640];            // max(Als+Bls = 16384, Cls = 16640)
    u16* Als = smem;                       // [128][64]
    u16* Bls = smem + 8192;                // [128][64]
    const int tid  = threadIdx.x;
    const int wave = tid >> 6, lane = tid & 63;
    const int wm = wave >> 1, wn = wave & 1;
    const int bm = blockIdx.x / grid_n, bn = blockIdx.x % grid_n;
    const int m0 = bm * 128, n0 = bn * 128;
    const int sr = lane >> 3, sc = lane & 7;       // staging: 8 rows x 8 chunks
    const int fr = lane & 15, kg = lane >> 4;      // fragment coords

    f32x4 acc[4][4];
#pragma unroll
    for (int i = 0; i < 4; i++)
#pragma unroll
        for (int j = 0; j < 4; j++) acc[i][j] = (f32x4){0.f, 0.f, 0.f, 0.f};

    for (int kk = 0; kk < K; kk += 64) {
#pragma unroll
        for (int i = 0; i < 4; i++) {
            int rl = wave * 32 + i * 8 + sr;
            int cs = sc ^ (rl & 7);                 // pre-swizzled global source
            gload16(A  + (size_t)(m0 + rl) * K + kk + cs * 8,
                    &Als[(wave * 32 + i * 8) * 64]);
            gload16(Wt + (size_t)(n0 + rl) * K + kk + cs * 8,
                    &Bls[(wave * 32 + i * 8) * 64]);
        }
        asm volatile("s_waitcnt vmcnt(0)" ::: "memory");
        __syncthreads();

#pragma unroll
        for (int k2 = 0; k2 < 2; k2++) {
            s16x8 af[4], bfr[4];
#pragma unroll
            for (int mi = 0; mi < 4; mi++) {
                int r = wm * 64 + mi * 16 + fr;
                int c = (k2 * 4 + kg) ^ (r & 7);    // swizzled read
                af[mi] = *(const s16x8*)&Als[r * 64 + c * 8];
            }
#pragma unroll
            for (int ni = 0; ni < 4; ni++) {
                int r = wn * 64 + ni * 16 + fr;
                int c = (k2 * 4 + kg) ^ (r & 7);
                bfr[ni] = *(const s16x8*)&Bls[r * 64 + c * 8];
            }
#pragma unroll
            for (int mi = 0; mi < 4; mi++)
#pragma unroll
                for (int ni = 0; ni < 4; ni++)
                    acc[mi][ni] = __builtin_amdgcn_mfma_f32_16x16x32_bf16(
                        af[mi], bfr[ni], acc[mi][ni], 0, 0, 0);
        }
        __syncthreads();
    }

    // epilogue: C row = kg*4 + j, col = fr (m89/m91-verified C/D layout)
    // bounce through LDS [128][130] for coalesced output
    u16* Cls = smem;
#pragma unroll
    for (int ni = 0; ni < 4; ni++) {
        int c = wn * 64 + ni * 16 + fr;
        float bv = 0.f;
        if constexpr (EPI == 0) bv = bias[n0 + c];
#pragma unroll
        for (int mi = 0; mi < 4; mi++) {
#pragma unroll
            for (int j = 0; j < 4; j++) {
                int r = wm * 64 + mi * 16 + kg * 4 + j;
                float v = acc[mi][ni][j];
                if constexpr (EPI == 0) {
                    v += bv;
                    v = v > 0.f ? v : 0.f;
                }
                Cls[r * 130 + c] = f2bf(v);
            }
        }
    }
    __syncthreads();

    const int r2 = tid >> 1;                  // 0..127
    const int cb = (tid & 1) * 64;            // two 64-col halves
    if (m0 + r2 < N_NODES) {
        u16* orow = (u16*)out + (size_t)(m0 + r2) * N + n0 + cb;
#pragma unroll
        for (int k = 0; k < 8; k++) {
            u16x8 val = *(const u16x8*)&Cls[r2 * 130 + cb + k * 8];
            *(u16x8*)(orow + k * 8) = val;
        }
    }
}

// ---------------- launch ----------------
extern "C" void kernel_launch(void* const* d_in, const int* in_sizes, int n_in,
                              void* d_out, int out_size, void* d_ws, size_t ws_size,
                              hipStream_t stream) {
    const float* x    = (const float*)d_in[0];
    const int*   src  = (const int*)d_in[1];
    const int*   dst  = (const int*)d_in[2];
    const float* w1   = (const float*)d_in[3];
    const float* b1   = (const float*)d_in[4];
    const float* eps1 = (const float*)d_in[5];
    const float* w2   = (const float*)d_in[6];
    const float* b2   = (const float*)d_in[7];
    const float* eps2 = (const float*)d_in[8];
    const float* w3   = (const float*)d_in[9];
    const float* b3   = (const float*)d_in[10];
    const float* eps3 = (const float*)d_in[11];

    char* ws = (char*)d_ws;
    size_t off = 0;
    auto take = [&](size_t bytes) {
        char* p = ws + off;
        off += (bytes + 255) & ~(size_t)255;
        return p;
    };
    const int TOT8 = N_NODES * NPASS;                 // 400000 buckets
    int* cnt8 = (int*)take((size_t)TOT8 * 4);
    int* rp8  = (int*)take((size_t)(TOT8 + 1) * 4);
    int* cur8 = (int*)take((size_t)TOT8 * 4);
    int* bsum = (int*)take(2048 * 4);
    int* col  = (int*)take((size_t)N_EDGES * 4);
    int* perm = (int*)take((size_t)N_NODES * 4);
    u16* w1t  = (u16*)take((size_t)IN_C * HID_C * 2);
    u16* w2t  = (u16*)take((size_t)HID_C * HID_C * 2);
    u16* w3t  = (u16*)take((size_t)HID_C * OUT_C * 2);
    u16* A0   = (u16*)take((size_t)M_PAD * IN_C * 2);
    u16* h1   = (u16*)take((size_t)M_PAD * HID_C * 2);
    u16* A1   = (u16*)take((size_t)M_PAD * HID_C * 2);
    // time-shared buffer: xb (phase 1) -> A1 (phase 2) -> g3 bf16 (phase 3).
    // each is fully dead before the next is written; stream order serializes.
    u16* xb = A1;            // 25.6 MB <= 51.2 MB, dead after l1 agg
    u16* h2 = h1;            // GEMM2 reads only A1 -> safe alias
    u16* g3 = A1;            // GEMM3 reads only h2 -> safe alias

    const int NB8 = (TOT8 + 255) / 256;   // 1563 scan blocks
    const int NE  = (N_EDGES + 255) / 256;
    const int NSEG = (N_NODES + SEG - 1) / SEG;   // 49 segments

    hipMemsetAsync(cnt8, 0, (size_t)TOT8 * 4, stream);
    k_hist8  <<<NE, 256, 0, stream>>>(src, dst, cnt8);
    k_partial<<<NB8, 256, 0, stream>>>(cnt8, bsum, TOT8);
    k_scanb  <<<1, 256, 0, stream>>>(bsum, NB8);
    k_rowptr8<<<NB8, 256, 0, stream>>>(cnt8, bsum, rp8, cur8, TOT8);
    k_scatter8<<<NE, 256, 0, stream>>>(src, dst, cur8, col);

    // segment-local degree sort (1 kernel, LDS-only atomics)
    k_locsort<<<NSEG, 256, 0, stream>>>(rp8, perm);

    // merged prep: 2048 weight-transpose blocks + 12500 x->bf16 blocks
    k_prep<<<2048 + 12500, 256, 0, stream>>>(w1, w2, w3, x, w1t, w2t, w3t, xb);

    // agg grids: 16 nodes/block; C=512 -> 3125 chunks x 8 slabs; C=256 -> x 4
    const int NCH  = (N_NODES + 15) / 16;   // 3125
    const int G512 = NCH * 8;
    const int G256 = NCH * 4;

    // layer 1: aggregate (256ch bf16) then GEMM -> h1 = relu(A0 @ W1 + b1)
    k_agg_stream<IN_C, 0><<<G256, 256, 0, stream>>>(
        xb, rp8, col, perm, eps1, nullptr, A0);
    gemm_k<IN_C, 0><<<391 * (HID_C / 128), 256, 0, stream>>>(
        A0, w1t, b1, h1, HID_C, HID_C / 128);

    // layer 2: aggregate (512ch) then GEMM -> h2 = relu(A1 @ W2 + b2)
    k_agg_stream<HID_C, 0><<<G512, 256, 0, stream>>>(
        h1, rp8, col, perm, eps2, nullptr, A1);
    gemm_k<HID_C, 0><<<391 * (HID_C / 128), 256, 0, stream>>>(
        A1, w2t, b2, h2, HID_C, HID_C / 128);

    // layer 3: GEMM first (g3 = h2 @ W3 bf16, no bias), then aggregate + bias -> fp32
    gemm_k<HID_C, 1><<<391 * (OUT_C / 128), 256, 0, stream>>>(
        h2, w3t, nullptr, g3, OUT_C, OUT_C / 128);
    k_agg_stream<OUT_C, 1><<<G256, 256, 0, stream>>>(
        g3, rp8, col, perm, eps3, b3, (float*)d_out);
}

// Round 12
// 421.417 us; speedup vs baseline: 1.1094x; 1.0445x over previous
//
#include <hip/hip_runtime.h>

#define N_NODES 50000
#define N_EDGES 800000
#define IN_C 256
#define HID_C 512
#define OUT_C 256
#define M_PAD 50048   // 391 * 128, covers 50000 with one padded tile
#define SEG 1024      // local degree-sort segment

typedef unsigned short u16;
typedef unsigned int   u32;
typedef u16  u16x4 __attribute__((ext_vector_type(4)));
typedef u16  u16x8 __attribute__((ext_vector_type(8)));
typedef short s16x8 __attribute__((ext_vector_type(8)));   // bf16 MFMA frag (guide §3)
typedef float f32x4 __attribute__((ext_vector_type(4)));

__device__ __forceinline__ float bf2f(u16 h) {
    u32 u = ((u32)h) << 16;
    return __builtin_bit_cast(float, u);
}
__device__ __forceinline__ u16 f2bf(float f) {   // round-to-nearest-even
    u32 u = __builtin_bit_cast(u32, f);
    u32 r = u + 0x7fffu + ((u >> 16) & 1u);
    return (u16)(r >> 16);
}
__device__ __forceinline__ void gload16(const void* g, void* l) {
    __builtin_amdgcn_global_load_lds(
        (const __attribute__((address_space(1))) u32*)g,
        (__attribute__((address_space(3))) u32*)l, 16, 0, 0);
}

// ---------------- CSR build (NPASS=1: sub-buckets were dead weight) ---------
__global__ void k_partial(const int* __restrict__ cnt, int* __restrict__ bsum, int total) {
    __shared__ int s[256];
    int i = blockIdx.x * 256 + threadIdx.x;
    int v = (i < total) ? cnt[i] : 0;
    s[threadIdx.x] = v; __syncthreads();
    for (int o = 128; o > 0; o >>= 1) {
        if (threadIdx.x < o) s[threadIdx.x] += s[threadIdx.x + o];
        __syncthreads();
    }
    if (threadIdx.x == 0) bsum[blockIdx.x] = s[0];
}

// exclusive scan of nb block sums (nb may exceed 256): chunked Hillis-Steele + carry
__global__ void k_scanb(int* __restrict__ bsum, int nb) {
    __shared__ int s[256];
    int carry = 0;
    for (int base = 0; base < nb; base += 256) {
        int i = base + threadIdx.x;
        int v = (i < nb) ? bsum[i] : 0;
        s[threadIdx.x] = v; __syncthreads();
        for (int o = 1; o < 256; o <<= 1) {
            int t = (threadIdx.x >= o) ? s[threadIdx.x - o] : 0;
            __syncthreads();
            s[threadIdx.x] += t;
            __syncthreads();
        }
        int tot = s[255];
        if (i < nb) bsum[i] = s[threadIdx.x] - v + carry;
        carry += tot;
        __syncthreads();
    }
}

__global__ void k_rowptr(const int* __restrict__ cnt, const int* __restrict__ bsum,
                         int* __restrict__ rp, int* __restrict__ cur, int total) {
    __shared__ int s[256];
    int i = blockIdx.x * 256 + threadIdx.x;
    int v = (i < total) ? cnt[i] : 0;
    s[threadIdx.x] = v; __syncthreads();
    for (int o = 1; o < 256; o <<= 1) {                     // Hillis-Steele inclusive
        int t = (threadIdx.x >= o) ? s[threadIdx.x - o] : 0;
        __syncthreads();
        s[threadIdx.x] += t;
        __syncthreads();
    }
    int excl = s[threadIdx.x] - v + bsum[blockIdx.x];
    if (i < total) { rp[i] = excl; cur[i] = excl; }
    if (i == total - 1) rp[total] = excl + v;
}

__global__ void k_scatter(const int* __restrict__ src, const int* __restrict__ dst,
                          int* __restrict__ cur, int* __restrict__ col) {
    int e = blockIdx.x * 256 + threadIdx.x;
    if (e < N_EDGES) {
        int p = atomicAdd(&cur[dst[e]], 1);
        col[p] = src[e];
    }
}

// ---- segment-local degree sort: convergence + locality (r11, kept) ----
__global__ __launch_bounds__(256) void k_locsort(const int* __restrict__ rp,
                                                 int* __restrict__ perm) {
    __shared__ int bins[256];
    __shared__ int s[256];
    const int t = threadIdx.x;
    const int n0 = blockIdx.x * SEG;
    bins[t] = 0; __syncthreads();
    int deg[4];
#pragma unroll
    for (int i = 0; i < 4; i++) {
        int n = n0 + i * 256 + t;
        deg[i] = 0;
        if (n < N_NODES) {
            int d = rp[n + 1] - rp[n];
            if (d > 255) d = 255;
            deg[i] = d;
            atomicAdd(&bins[d], 1);        // LDS atomic
        }
    }
    __syncthreads();
    int v = bins[t];
    s[t] = v; __syncthreads();
    for (int o = 1; o < 256; o <<= 1) {    // Hillis-Steele inclusive scan
        int u = (t >= o) ? s[t - o] : 0;
        __syncthreads();
        s[t] += u;
        __syncthreads();
    }
    bins[t] = s[t] - v;                    // exclusive base -> running counter
    __syncthreads();
#pragma unroll
    for (int i = 0; i < 4; i++) {
        int n = n0 + i * 256 + t;
        if (n < N_NODES) {
            int pos = atomicAdd(&bins[deg[i]], 1);
            perm[n0 + pos] = n;
        }
    }
}

// -- merged prep: w-transposes + x->bf16 + edge histogram (one launch) --
__device__ __forceinline__ void wt_body(const float* w, u16* wt, int K, int N, int idx) {
    if (idx >= K * N) return;
    int n = idx / K, k = idx - n * K;
    wt[idx] = f2bf(w[(size_t)k * N + n]);
}

#define PREP_W  2048    // 512 + 1024 + 512 weight blocks
#define PREP_X  12500   // x -> bf16 blocks
#define PREP_H  3125    // histogram blocks

__global__ void k_prep(const float* __restrict__ w1, const float* __restrict__ w2,
                       const float* __restrict__ w3, const float* __restrict__ x,
                       const int* __restrict__ dst,
                       u16* __restrict__ w1t, u16* __restrict__ w2t,
                       u16* __restrict__ w3t, u16* __restrict__ xb,
                       int* __restrict__ cnt) {
    int b = blockIdx.x, t = threadIdx.x;
    if (b < 512) {
        wt_body(w1, w1t, IN_C, HID_C, b * 256 + t);
    } else if (b < 1536) {
        wt_body(w2, w2t, HID_C, HID_C, (b - 512) * 256 + t);
    } else if (b < 2048) {
        wt_body(w3, w3t, HID_C, OUT_C, (b - 1536) * 256 + t);
    } else if (b < PREP_W + PREP_X) {
        int i = (b - PREP_W) * 256 + t;
        if (i < N_NODES * IN_C / 4) {
            float4 v = ((const float4*)x)[i];
            u16x4 o;
            o[0] = f2bf(v.x); o[1] = f2bf(v.y); o[2] = f2bf(v.z); o[3] = f2bf(v.w);
            ((u16x4*)xb)[i] = o;
        }
    } else {
        int e = (b - PREP_W - PREP_X) * 256 + t;
        if (e < N_EDGES) atomicAdd(&cnt[dst[e]], 1);
    }
}

// ---- streaming slab gather (XCD-private lines + segment-local degree sort) ----
// 128-B slabs: C=512 -> 8 slabs, slab=bid&7 -> each line pulled by exactly one
// XCD; C=256 -> 4 slabs, 2 XCDs per slab.
// One node per 16-lane group (16 nodes/block); lane owns 4 ch (8 B).
// EPI 0: out bf16 = bf16(ep*self + agg).  EPI 1: out fp32 = ep*self + agg + bias.
template <int C, int EPI>
__global__ __launch_bounds__(256) void k_agg_stream(
    const u16* __restrict__ sm, const int* __restrict__ rp,
    const int* __restrict__ col, const int* __restrict__ perm,
    const float* __restrict__ eps, const float* __restrict__ bias,
    void* __restrict__ out) {
    constexpr int NSLAB = C / 64;          // 128-B slabs
    const int slab  = blockIdx.x & (NSLAB - 1);
    const int chunk = blockIdx.x / NSLAB;
    const int gid = threadIdx.x >> 4;      // 16 groups of 16 lanes
    const int ln  = threadIdx.x & 15;
    const int ch0 = slab * 64 + ln * 4;
    const int ni = chunk * 16 + gid;
    if (ni >= N_NODES) return;
    const int n = perm[ni];
    const float ep = 1.f + eps[0];

    const int rs = rp[n];
    const int re = rp[n + 1];
    float a0 = 0.f, a1 = 0.f, a2 = 0.f, a3 = 0.f;
    int e = rs;
    for (; e + 4 <= re; e += 4) {
        int s0 = col[e], s1 = col[e + 1], s2 = col[e + 2], s3 = col[e + 3];
        u16x4 v0 = *(const u16x4*)(sm + (size_t)s0 * C + ch0);
        u16x4 v1 = *(const u16x4*)(sm + (size_t)s1 * C + ch0);
        u16x4 v2 = *(const u16x4*)(sm + (size_t)s2 * C + ch0);
        u16x4 v3 = *(const u16x4*)(sm + (size_t)s3 * C + ch0);
        a0 += bf2f(v0[0]) + bf2f(v1[0]) + bf2f(v2[0]) + bf2f(v3[0]);
        a1 += bf2f(v0[1]) + bf2f(v1[1]) + bf2f(v2[1]) + bf2f(v3[1]);
        a2 += bf2f(v0[2]) + bf2f(v1[2]) + bf2f(v2[2]) + bf2f(v3[2]);
        a3 += bf2f(v0[3]) + bf2f(v1[3]) + bf2f(v2[3]) + bf2f(v3[3]);
    }
    for (; e < re; e++) {
        int s0 = col[e];
        u16x4 v0 = *(const u16x4*)(sm + (size_t)s0 * C + ch0);
        a0 += bf2f(v0[0]); a1 += bf2f(v0[1]); a2 += bf2f(v0[2]); a3 += bf2f(v0[3]);
    }

    u16x4 sv = *(const u16x4*)(sm + (size_t)n * C + ch0);
    float r0 = fmaf(ep, bf2f(sv[0]), a0);
    float r1 = fmaf(ep, bf2f(sv[1]), a1);
    float r2 = fmaf(ep, bf2f(sv[2]), a2);
    float r3 = fmaf(ep, bf2f(sv[3]), a3);
    if constexpr (EPI == 0) {
        u16x4 o;
        o[0] = f2bf(r0); o[1] = f2bf(r1); o[2] = f2bf(r2); o[3] = f2bf(r3);
        *(u16x4*)((u16*)out + (size_t)n * C + ch0) = o;
    } else {
        float4 bv = *(const float4*)(bias + ch0);
        float4 o;
        o.x = r0 + bv.x; o.y = r1 + bv.y; o.z = r2 + bv.z; o.w = r3 + bv.w;
        *(float4*)((float*)out + (size_t)n * C + ch0) = o;
    }
}

// -------------- bf16 MFMA GEMM: C[M][N] = A[M][K] @ Wt[N][K]^T --------------
// 128x128 tile, BK=64 (32 MFMA per vmcnt/barrier drain), 4 waves (2x2).
// Staging: global_load_lds w16, linear LDS dest, chunk-XOR swizzle c^=(r&7)
// applied on BOTH global source and ds_read (rule 21) -> 2-way (free) banks.
// Epilogue: acc -> bf16 -> LDS C-tile [128][130] (pad => conflict-free b128
// readback), then coalesced u16x8 global stores.
// EPI=0: out bf16 = relu(acc + bias).  EPI=1: out bf16 = acc.
template <int K, int EPI>
__global__ __launch_bounds__(256, 2) void gemm_k(
    const u16* __restrict__ A, const u16* __restrict__ Wt,
    const float* __restrict__ bias, void* __restrict__ out,
    int N, int grid_n) {
    __shared__ u16 smem[16640];            // max(Als+Bls = 16384, Cls = 16640)
    u16* Als = smem;                       // [128][64]
    u16* Bls = smem + 8192;                // [128][64]
    const int tid  = threadIdx.x;
    const int wave = tid >> 6, lane = tid & 63;
    const int wm = wave >> 1, wn = wave & 1;
    const int bm = blockIdx.x / grid_n, bn = blockIdx.x % grid_n;
    const int m0 = bm * 128, n0 = bn * 128;
    const int sr = lane >> 3, sc = lane & 7;       // staging: 8 rows x 8 chunks
    const int fr = lane & 15, kg = lane >> 4;      // fragment coords

    f32x4 acc[4][4];
#pragma unroll
    for (int i = 0; i < 4; i++)
#pragma unroll
        for (int j = 0; j < 4; j++) acc[i][j] = (f32x4){0.f, 0.f, 0.f, 0.f};

    for (int kk = 0; kk < K; kk += 64) {
#pragma unroll
        for (int i = 0; i < 4; i++) {
            int rl = wave * 32 + i * 8 + sr;
            int cs = sc ^ (rl & 7);                 // pre-swizzled global source
            gload16(A  + (size_t)(m0 + rl) * K + kk + cs * 8,
                    &Als[(wave * 32 + i * 8) * 64]);
            gload16(Wt + (size_t)(n0 + rl) * K + kk + cs * 8,
                    &Bls[(wave * 32 + i * 8) * 64]);
        }
        asm volatile("s_waitcnt vmcnt(0)" ::: "memory");
        __syncthreads();

#pragma unroll
        for (int k2 = 0; k2 < 2; k2++) {
            s16x8 af[4], bfr[4];
#pragma unroll
            for (int mi = 0; mi < 4; mi++) {
                int r = wm * 64 + mi * 16 + fr;
                int c = (k2 * 4 + kg) ^ (r & 7);    // swizzled read
                af[mi] = *(const s16x8*)&Als[r * 64 + c * 8];
            }
#pragma unroll
            for (int ni = 0; ni < 4; ni++) {
                int r = wn * 64 + ni * 16 + fr;
                int c = (k2 * 4 + kg) ^ (r & 7);
                bfr[ni] = *(const s16x8*)&Bls[r * 64 + c * 8];
            }
#pragma unroll
            for (int mi = 0; mi < 4; mi++)
#pragma unroll
                for (int ni = 0; ni < 4; ni++)
                    acc[mi][ni] = __builtin_amdgcn_mfma_f32_16x16x32_bf16(
                        af[mi], bfr[ni], acc[mi][ni], 0, 0, 0);
        }
        __syncthreads();
    }

    // epilogue: C row = kg*4 + j, col = fr (m89/m91-verified C/D layout)
    // bounce through LDS [128][130] for coalesced output
    u16* Cls = smem;
#pragma unroll
    for (int ni = 0; ni < 4; ni++) {
        int c = wn * 64 + ni * 16 + fr;
        float bv = 0.f;
        if constexpr (EPI == 0) bv = bias[n0 + c];
#pragma unroll
        for (int mi = 0; mi < 4; mi++) {
#pragma unroll
            for (int j = 0; j < 4; j++) {
                int r = wm * 64 + mi * 16 + kg * 4 + j;
                float v = acc[mi][ni][j];
                if constexpr (EPI == 0) {
                    v += bv;
                    v = v > 0.f ? v : 0.f;
                }
                Cls[r * 130 + c] = f2bf(v);
            }
        }
    }
    __syncthreads();

    const int r2 = tid >> 1;                  // 0..127
    const int cb = (tid & 1) * 64;            // two 64-col halves
    if (m0 + r2 < N_NODES) {
        u16* orow = (u16*)out + (size_t)(m0 + r2) * N + n0 + cb;
#pragma unroll
        for (int k = 0; k < 8; k++) {
            u16x8 val = *(const u16x8*)&Cls[r2 * 130 + cb + k * 8];
            *(u16x8*)(orow + k * 8) = val;
        }
    }
}

// ---------------- launch ----------------
extern "C" void kernel_launch(void* const* d_in, const int* in_sizes, int n_in,
                              void* d_out, int out_size, void* d_ws, size_t ws_size,
                              hipStream_t stream) {
    const float* x    = (const float*)d_in[0];
    const int*   src  = (const int*)d_in[1];
    const int*   dst  = (const int*)d_in[2];
    const float* w1   = (const float*)d_in[3];
    const float* b1   = (const float*)d_in[4];
    const float* eps1 = (const float*)d_in[5];
    const float* w2   = (const float*)d_in[6];
    const float* b2   = (const float*)d_in[7];
    const float* eps2 = (const float*)d_in[8];
    const float* w3   = (const float*)d_in[9];
    const float* b3   = (const float*)d_in[10];
    const float* eps3 = (const float*)d_in[11];

    char* ws = (char*)d_ws;
    size_t off = 0;
    auto take = [&](size_t bytes) {
        char* p = ws + off;
        off += (bytes + 255) & ~(size_t)255;
        return p;
    };
    int* cnt  = (int*)take((size_t)N_NODES * 4);
    int* rp   = (int*)take((size_t)(N_NODES + 1) * 4);
    int* cur  = (int*)take((size_t)N_NODES * 4);
    int* bsum = (int*)take(2048 * 4);
    int* col  = (int*)take((size_t)N_EDGES * 4);
    int* perm = (int*)take((size_t)N_NODES * 4);
    u16* w1t  = (u16*)take((size_t)IN_C * HID_C * 2);
    u16* w2t  = (u16*)take((size_t)HID_C * HID_C * 2);
    u16* w3t  = (u16*)take((size_t)HID_C * OUT_C * 2);
    u16* A0   = (u16*)take((size_t)M_PAD * IN_C * 2);
    u16* h1   = (u16*)take((size_t)M_PAD * HID_C * 2);
    u16* A1   = (u16*)take((size_t)M_PAD * HID_C * 2);
    // time-shared buffer: xb (phase 1) -> A1 (phase 2) -> g3 bf16 (phase 3).
    // each is fully dead before the next is written; stream order serializes.
    u16* xb = A1;            // 25.6 MB <= 51.2 MB, dead after l1 agg
    u16* h2 = h1;            // GEMM2 reads only A1 -> safe alias
    u16* g3 = A1;            // GEMM3 reads only h2 -> safe alias

    const int NB   = (N_NODES + 255) / 256;       // 196 scan blocks
    const int NE   = (N_EDGES + 255) / 256;       // 3125
    const int NSEG = (N_NODES + SEG - 1) / SEG;   // 49 segments

    hipMemsetAsync(cnt, 0, (size_t)N_NODES * 4, stream);

    // fused prep: weight transposes + x->bf16 + edge histogram
    k_prep<<<PREP_W + PREP_X + PREP_H, 256, 0, stream>>>(
        w1, w2, w3, x, dst, w1t, w2t, w3t, xb, cnt);

    k_partial<<<NB, 256, 0, stream>>>(cnt, bsum, N_NODES);
    k_scanb  <<<1, 256, 0, stream>>>(bsum, NB);
    k_rowptr <<<NB, 256, 0, stream>>>(cnt, bsum, rp, cur, N_NODES);
    k_scatter<<<NE, 256, 0, stream>>>(src, dst, cur, col);

    // segment-local degree sort (1 kernel, LDS-only atomics)
    k_locsort<<<NSEG, 256, 0, stream>>>(rp, perm);

    // agg grids: 16 nodes/block; C=512 -> 3125 chunks x 8 slabs; C=256 -> x 4
    const int NCH  = (N_NODES + 15) / 16;   // 3125
    const int G512 = NCH * 8;
    const int G256 = NCH * 4;

    // layer 1: aggregate (256ch bf16) then GEMM -> h1 = relu(A0 @ W1 + b1)
    k_agg_stream<IN_C, 0><<<G256, 256, 0, stream>>>(
        xb, rp, col, perm, eps1, nullptr, A0);
    gemm_k<IN_C, 0><<<391 * (HID_C / 128), 256, 0, stream>>>(
        A0, w1t, b1, h1, HID_C, HID_C / 128);

    // layer 2: aggregate (512ch) then GEMM -> h2 = relu(A1 @ W2 + b2)
    k_agg_stream<HID_C, 0><<<G512, 256, 0, stream>>>(
        h1, rp, col, perm, eps2, nullptr, A1);
    gemm_k<HID_C, 0><<<391 * (HID_C / 128), 256, 0, stream>>>(
        A1, w2t, b2, h2, HID_C, HID_C / 128);

    // layer 3: GEMM first (g3 = h2 @ W3 bf16, no bias), then aggregate + bias -> fp32
    gemm_k<HID_C, 1><<<391 * (OUT_C / 128), 256, 0, stream>>>(
        h2, w3t, nullptr, g3, OUT_C, OUT_C / 128);
    k_agg_stream<OUT_C, 1><<<G256, 256, 0, stream>>>(
        g3, rp, col, perm, eps3, b3, (float*)d_out);
}